// Round 15
// baseline (308.986 us; speedup 1.0000x reference)
//
#include <hip/hip_runtime.h>
#include <hip/hip_bf16.h>

#define N_NODES 100000
#define D 256
#define R_REL 8
#define E_EDGES 40000
#define LN_EPS 1e-5f
#define ETOT (R_REL * E_EDGES)                    // 320000
#define SCAN_CH 1024
#define SCAN_NB ((N_NODES + SCAN_CH - 1) / SCAN_CH)  // 98
#define NROWT ((N_NODES + 127) / 128)             // 782
#define NWG (NROWT * 10)                          // 7820
#define PREPX_NB (N_NODES * D / 8 / 256)          // 12500
#define PREPB_NB 80
#define COUNT_NB ((ETOT + 255) / 256)             // 1250

typedef __attribute__((ext_vector_type(8))) short short8;
typedef __attribute__((ext_vector_type(4))) float f32x4;
typedef __attribute__((ext_vector_type(2))) float f32x2;
typedef unsigned char uchar;

__device__ inline ushort bf16u(float f) {
    __hip_bfloat16 h = __float2bfloat16(f);
    return *reinterpret_cast<ushort*>(&h);
}
__device__ inline float bf2f(ushort u) { return __uint_as_float(((unsigned)u) << 16); }

// ---------------------------------------------------------------------------
// Fused prep: [0, PREPX_NB) x->xb bf16 | [.., +PREPB_NB) BT transpose |
// [.., +COUNT_NB) per-(dst,r) histogram.  All independent.
__global__ __launch_bounds__(256) void k_prep(const float* __restrict__ x,
                                              ushort* __restrict__ xb,
                                              const float* __restrict__ w_self,
                                              const float* __restrict__ bases,
                                              ushort* __restrict__ BT,
                                              const int* __restrict__ ei,
                                              int* __restrict__ cntR) {
    __shared__ float tile[64][65];
    int b = blockIdx.x;
    int t = threadIdx.x;
    if (b < PREPX_NB) {
        size_t idx = (size_t)b * 256 + t;
        const float4* xp = (const float4*)(x + idx * 8);
        float4 f0 = xp[0], f1 = xp[1];
        short8 v;
        v[0] = (short)bf16u(f0.x); v[1] = (short)bf16u(f0.y);
        v[2] = (short)bf16u(f0.z); v[3] = (short)bf16u(f0.w);
        v[4] = (short)bf16u(f1.x); v[5] = (short)bf16u(f1.y);
        v[6] = (short)bf16u(f1.z); v[7] = (short)bf16u(f1.w);
        *(short8*)(xb + idx * 8) = v;
    } else if (b < PREPX_NB + PREPB_NB) {
        int bb = b - PREPX_NB;
        int ot = bb >> 2, dt = bb & 3;
        int o0 = ot * 64, d0 = dt * 64;
        int m = o0 >> 8;                   // 0 = w_self, 1..4 = bases[m-1]
        const float* src = (m == 0) ? w_self : bases + (size_t)(m - 1) * D * D;
        int ol0 = o0 & 255;
        int cl = t & 63, rw = t >> 6;
        for (int i = 0; i < 16; ++i) {
            int dl = i * 4 + rw;
            tile[dl][cl] = src[(size_t)(d0 + dl) * D + ol0 + cl];
        }
        __syncthreads();
        for (int i = 0; i < 16; ++i) {
            int ol = i * 4 + rw;
            BT[(size_t)(o0 + ol) * D + d0 + cl] = bf16u(tile[cl][ol]);
        }
    } else {
        int idx = (b - PREPX_NB - PREPB_NB) * 256 + t;
        if (idx < ETOT) {
            int r = idx / E_EDGES, e = idx % E_EDGES;
            int dst = ei[(r * 2 + 1) * E_EDGES + e];
            atomicAdd(&cntR[(size_t)dst * 8 + r], 1);
        }
    }
}

// ---------------------------------------------------------------------------
// scanA: per-node degree = sum of cntR[node][0..7], then block exclusive scan.
__global__ __launch_bounds__(256) void k_scanA(const int* __restrict__ cntR,
                                               int* __restrict__ start,
                                               int* __restrict__ sumsA) {
    __shared__ int sc[256];
    int t = threadIdx.x;
    int base = blockIdx.x * SCAN_CH + t * 4;
    int v[4];
#pragma unroll
    for (int i = 0; i < 4; ++i) {
        int node = base + i;
        int s = 0;
        if (node < N_NODES) {
            const int4* c = (const int4*)&cntR[(size_t)node * 8];
            int4 a = c[0], b = c[1];
            s = a.x + a.y + a.z + a.w + b.x + b.y + b.z + b.w;
        }
        v[i] = s;
    }
    int ts = v[0] + v[1] + v[2] + v[3];
    sc[t] = ts;
    __syncthreads();
    for (int off = 1; off < 256; off <<= 1) {
        int val = (t >= off) ? sc[t - off] : 0;
        __syncthreads();
        sc[t] += val;
        __syncthreads();
    }
    int excl = sc[t] - ts;
    if (base + 0 < N_NODES) start[base + 0] = excl;
    if (base + 1 < N_NODES) start[base + 1] = excl + v[0];
    if (base + 2 < N_NODES) start[base + 2] = excl + v[0] + v[1];
    if (base + 3 < N_NODES) start[base + 3] = excl + v[0] + v[1] + v[2];
    if (t == 255) sumsA[blockIdx.x] = sc[255];
}

__global__ __launch_bounds__(256) void k_scanB(const int* __restrict__ sumsA,
                                               int* __restrict__ sumsB) {
    __shared__ int sc[256];
    int t = threadIdx.x;
    int i0 = t * 4;
    int v0 = (i0 + 0 < SCAN_NB) ? sumsA[i0 + 0] : 0;
    int v1 = (i0 + 1 < SCAN_NB) ? sumsA[i0 + 1] : 0;
    int v2 = (i0 + 2 < SCAN_NB) ? sumsA[i0 + 2] : 0;
    int v3 = (i0 + 3 < SCAN_NB) ? sumsA[i0 + 3] : 0;
    int ts = v0 + v1 + v2 + v3;
    sc[t] = ts;
    __syncthreads();
    for (int off = 1; off < 256; off <<= 1) {
        int val = (t >= off) ? sc[t - off] : 0;
        __syncthreads();
        sc[t] += val;
        __syncthreads();
    }
    int excl = sc[t] - ts;
    if (i0 + 0 < SCAN_NB) sumsB[i0 + 0] = excl;
    if (i0 + 1 < SCAN_NB) sumsB[i0 + 1] = excl + v0;
    if (i0 + 2 < SCAN_NB) sumsB[i0 + 2] = excl + v0 + v1;
    if (i0 + 3 < SCAN_NB) sumsB[i0 + 3] = excl + v0 + v1 + v2;
}

__global__ __launch_bounds__(256) void k_scanC(int* __restrict__ start,
                                               const int* __restrict__ sumsB,
                                               int* __restrict__ cursor) {
    int idx = blockIdx.x * blockDim.x + threadIdx.x;
    if (idx < N_NODES) {
        int v = start[idx] + sumsB[idx / SCAN_CH];
        start[idx] = v;
        cursor[idx] = v;
    }
    if (idx == 0) start[N_NODES] = ETOT;
}

// pairs[pos] = {(r<<20)|src, f32 bits of 1/(64*deg_{r,dst})}
__global__ void k_scatter(const int* __restrict__ ei, int* __restrict__ cursor,
                          const int* __restrict__ cntR, int2* __restrict__ pairs) {
    int idx = blockIdx.x * blockDim.x + threadIdx.x;
    if (idx >= ETOT) return;
    int r = idx / E_EDGES, e = idx % E_EDGES;
    int src = ei[r * 2 * E_EDGES + e];
    int dst = ei[(r * 2 + 1) * E_EDGES + e];
    int pos = atomicAdd(&cursor[dst], 1);
    float invd = __builtin_amdgcn_rcpf((float)cntR[(size_t)dst * 8 + r]) * 0.015625f;
    pairs[pos] = make_int2((r << 20) | src, __float_as_int(invd));
}

// ---------------------------------------------------------------------------
// [hb | U] = xb @ BT^T.  128x128 tile, BK=32, 32 KB LDS total -> 5 blocks/CU
// (20 waves/CU) for barrier-latency hiding.  LDS tile layout: 16B chunks,
// column-major in K-slots: addr(row, ks) = (ks*128 + row)*16 -- linear dest
// for global_load_lds, conflict-free 256B-contiguous fragment reads.
// m204 bijective XCD swizzle + sigma output layout (unchanged from R12).
__global__ __launch_bounds__(256, 5) void k_gemm(const ushort* __restrict__ xb,
                                                 const ushort* __restrict__ BT,
                                                 ushort* __restrict__ hb,
                                                 uchar* __restrict__ U) {
    __shared__ ushort As[2][128 * 32];     // 2 x 8 KB
    __shared__ ushort Bs[2][128 * 32];     // 2 x 8 KB
    int t = threadIdx.x;

    const int q = NWG / 8, r8 = NWG % 8;
    int dd = blockIdx.x;
    int xcd = dd & 7, slot = dd >> 3;
    int wgid = (xcd < r8 ? xcd * (q + 1) : r8 * (q + 1) + (xcd - r8) * q) + slot;
    int rowtile = wgid / 10, pass = wgid % 10;
    int row0 = rowtile * 128;

    int l = t & 63, w = t >> 6;
    int wr = w >> 1, wc = w & 1;           // 2 x 2 wave grid
    int lr = l & 15, lg = l >> 4;

    // staging: 512 chunks of 16B per 8KB tile; thread t does chunks t, t+256.
    // chunk c -> row = c & 127, ks = c >> 7; dest byte = c*16 (linear).
    auto stageA = [&](int buf, int kt) {
#pragma unroll
        for (int p = 0; p < 2; ++p) {
            int c = p * 256 + t;
            int row = c & 127, ks = c >> 7;
            int srcrow = min(row0 + row, N_NODES - 1);
            const char* gp = (const char*)xb +
                ((size_t)srcrow * D + kt * 32 + ks * 8) * 2;
            char* lp = (char*)&As[buf][0] + p * 4096 + (t >> 6) * 1024;  // wave-uniform
            __builtin_amdgcn_global_load_lds(
                (const __attribute__((address_space(1))) void*)gp,
                (__attribute__((address_space(3))) void*)lp, 16, 0, 0);
        }
    };
    auto stageB = [&](int buf, int kt) {
#pragma unroll
        for (int p = 0; p < 2; ++p) {
            int c = p * 256 + t;
            int row = c & 127, ks = c >> 7;
            const char* gp = (const char*)BT +
                ((size_t)(pass * 128 + row) * D + kt * 32 + ks * 8) * 2;
            char* lp = (char*)&Bs[buf][0] + p * 4096 + (t >> 6) * 1024;
            __builtin_amdgcn_global_load_lds(
                (const __attribute__((address_space(1))) void*)gp,
                (__attribute__((address_space(3))) void*)lp, 16, 0, 0);
        }
    };

    f32x4 acc[4][4] = {};                  // [mi][ni]
    stageA(0, 0); stageB(0, 0);
    int buf = 0;
    for (int kt = 0; kt < 8; ++kt) {
        __syncthreads();                   // buf ready; prior reads of buf^1 done
        if (kt < 7) { stageA(buf ^ 1, kt + 1); stageB(buf ^ 1, kt + 1); }
        int koff = lg * 2048;              // ks = lg
        short8 a[4], b[4];
#pragma unroll
        for (int mi = 0; mi < 4; ++mi)
            a[mi] = *(const short8*)((const char*)&As[buf][0] +
                     koff + (wr * 64 + mi * 16 + lr) * 16);
#pragma unroll
        for (int ni = 0; ni < 4; ++ni)
            b[ni] = *(const short8*)((const char*)&Bs[buf][0] +
                     koff + (wc * 64 + ni * 16 + lr) * 16);
#pragma unroll
        for (int mi = 0; mi < 4; ++mi)
#pragma unroll
            for (int ni = 0; ni < 4; ++ni)
                acc[mi][ni] = __builtin_amdgcn_mfma_f32_16x16x32_bf16(
                    a[mi], b[ni], acc[mi][ni], 0, 0, 0);
        buf ^= 1;
    }

    // ---- epilogue (sigma layout; node = row0 + wr*64 + mi*16 + lg*4 + j)
    if (pass < 2) {
        int qbase = pass * 128 + wc * 64 + lr * 4;
#pragma unroll
        for (int mi = 0; mi < 4; ++mi)
#pragma unroll
            for (int j = 0; j < 4; ++j) {
                int node = row0 + wr * 64 + mi * 16 + lg * 4 + j;
                if (node < N_NODES) {
                    ushort4 v4;
                    v4.x = bf16u(acc[mi][0][j]);
                    v4.y = bf16u(acc[mi][1][j]);
                    v4.z = bf16u(acc[mi][2][j]);
                    v4.w = bf16u(acc[mi][3][j]);
                    *(ushort4*)&hb[(size_t)node * D + qbase] = v4;
                }
            }
    } else {
        int pl = pass - 2;
        int qbase = (pl >> 1) * 256 + (pl & 1) * 128 + wc * 64 + lr * 4;
#pragma unroll
        for (int mi = 0; mi < 4; ++mi)
#pragma unroll
            for (int j = 0; j < 4; ++j) {
                int node = row0 + wr * 64 + mi * 16 + lg * 4 + j;
                if (node < N_NODES) {
                    unsigned d = __builtin_amdgcn_cvt_pk_fp8_f32(
                        acc[mi][0][j] * 64.0f, acc[mi][1][j] * 64.0f, 0, false);
                    d = __builtin_amdgcn_cvt_pk_fp8_f32(
                        acc[mi][2][j] * 64.0f, acc[mi][3][j] * 64.0f, d, true);
                    *(unsigned*)&U[(size_t)node * 1024 + qbase] = d;
                }
            }
    }
}

// ---------------------------------------------------------------------------
// Per dst node (one wave each). 2-edge unrolled gather (8 U-dwords in flight),
// packed fp8 decode + pk_fma accumulate, hoisted tail loads, fast SiLU.
__global__ __launch_bounds__(256) void k_final(float* __restrict__ out,
                                               const ushort* __restrict__ hb,
                                               const uchar* __restrict__ U,
                                               const int* __restrict__ start,
                                               const int2* __restrict__ pairs,
                                               const float* __restrict__ coeff,
                                               const float* __restrict__ bias,
                                               const float* __restrict__ gamma,
                                               const float* __restrict__ beta) {
    __shared__ float cf[32];
    int t = threadIdx.x;
    if (t < 32) cf[t] = coeff[t];
    __syncthreads();
    int lane = t & 63, w = t >> 6;
    int n = blockIdx.x * 4 + w;
    int s = start[n], e = start[n + 1];

    // hoisted tail loads (latency hides under the gather)
    int c0 = (lane >> 4) * 64 + (lane & 15);
    size_t rowo = (size_t)n * D;
    ushort4 hu = *(const ushort4*)&hb[rowo + lane * 4];
    float bb0 = bias[c0], bb1 = bias[c0 + 16], bb2 = bias[c0 + 32], bb3 = bias[c0 + 48];

    f32x2 a01 = {0.f, 0.f}, a23 = {0.f, 0.f};
    const uchar* Ul = U + lane * 4;
    int p = s;
    for (; p + 1 < e; p += 2) {
        int2 cA = pairs[p], cB = pairs[p + 1];
        const uchar* upA = Ul + ((size_t)(cA.x & 0xFFFFF) << 10);
        const uchar* upB = Ul + ((size_t)(cB.x & 0xFFFFF) << 10);
        unsigned vA0 = *(const unsigned*)(upA);
        unsigned vA1 = *(const unsigned*)(upA + 256);
        unsigned vA2 = *(const unsigned*)(upA + 512);
        unsigned vA3 = *(const unsigned*)(upA + 768);
        unsigned vB0 = *(const unsigned*)(upB);
        unsigned vB1 = *(const unsigned*)(upB + 256);
        unsigned vB2 = *(const unsigned*)(upB + 512);
        unsigned vB3 = *(const unsigned*)(upB + 768);
        float invA = __int_as_float(cA.y);
        float invB = __int_as_float(cB.y);
        const float* wvA = &cf[(cA.x >> 20) * 4];
        const float* wvB = &cf[(cB.x >> 20) * 4];
        f32x2 wp;
        float ww;
        ww = wvA[0] * invA; wp[0] = ww; wp[1] = ww;
        a01 += wp * __builtin_amdgcn_cvt_pk_f32_fp8(vA0, false);
        a23 += wp * __builtin_amdgcn_cvt_pk_f32_fp8(vA0, true);
        ww = wvA[1] * invA; wp[0] = ww; wp[1] = ww;
        a01 += wp * __builtin_amdgcn_cvt_pk_f32_fp8(vA1, false);
        a23 += wp * __builtin_amdgcn_cvt_pk_f32_fp8(vA1, true);
        ww = wvA[2] * invA; wp[0] = ww; wp[1] = ww;
        a01 += wp * __builtin_amdgcn_cvt_pk_f32_fp8(vA2, false);
        a23 += wp * __builtin_amdgcn_cvt_pk_f32_fp8(vA2, true);
        ww = wvA[3] * invA; wp[0] = ww; wp[1] = ww;
        a01 += wp * __builtin_amdgcn_cvt_pk_f32_fp8(vA3, false);
        a23 += wp * __builtin_amdgcn_cvt_pk_f32_fp8(vA3, true);
        ww = wvB[0] * invB; wp[0] = ww; wp[1] = ww;
        a01 += wp * __builtin_amdgcn_cvt_pk_f32_fp8(vB0, false);
        a23 += wp * __builtin_amdgcn_cvt_pk_f32_fp8(vB0, true);
        ww = wvB[1] * invB; wp[0] = ww; wp[1] = ww;
        a01 += wp * __builtin_amdgcn_cvt_pk_f32_fp8(vB1, false);
        a23 += wp * __builtin_amdgcn_cvt_pk_f32_fp8(vB1, true);
        ww = wvB[2] * invB; wp[0] = ww; wp[1] = ww;
        a01 += wp * __builtin_amdgcn_cvt_pk_f32_fp8(vB2, false);
        a23 += wp * __builtin_amdgcn_cvt_pk_f32_fp8(vB2, true);
        ww = wvB[3] * invB; wp[0] = ww; wp[1] = ww;
        a01 += wp * __builtin_amdgcn_cvt_pk_f32_fp8(vB3, false);
        a23 += wp * __builtin_amdgcn_cvt_pk_f32_fp8(vB3, true);
    }
    if (p < e) {
        int2 cA = pairs[p];
        const uchar* upA = Ul + ((size_t)(cA.x & 0xFFFFF) << 10);
        unsigned vA0 = *(const unsigned*)(upA);
        unsigned vA1 = *(const unsigned*)(upA + 256);
        unsigned vA2 = *(const unsigned*)(upA + 512);
        unsigned vA3 = *(const unsigned*)(upA + 768);
        float invA = __int_as_float(cA.y);
        const float* wvA = &cf[(cA.x >> 20) * 4];
        f32x2 wp;
        float ww;
        ww = wvA[0] * invA; wp[0] = ww; wp[1] = ww;
        a01 += wp * __builtin_amdgcn_cvt_pk_f32_fp8(vA0, false);
        a23 += wp * __builtin_amdgcn_cvt_pk_f32_fp8(vA0, true);
        ww = wvA[1] * invA; wp[0] = ww; wp[1] = ww;
        a01 += wp * __builtin_amdgcn_cvt_pk_f32_fp8(vA1, false);
        a23 += wp * __builtin_amdgcn_cvt_pk_f32_fp8(vA1, true);
        ww = wvA[2] * invA; wp[0] = ww; wp[1] = ww;
        a01 += wp * __builtin_amdgcn_cvt_pk_f32_fp8(vA2, false);
        a23 += wp * __builtin_amdgcn_cvt_pk_f32_fp8(vA2, true);
        ww = wvA[3] * invA; wp[0] = ww; wp[1] = ww;
        a01 += wp * __builtin_amdgcn_cvt_pk_f32_fp8(vA3, false);
        a23 += wp * __builtin_amdgcn_cvt_pk_f32_fp8(vA3, true);
    }

    float a[4];
    a[0] = bf2f(hu.x) + bb0 + a01[0];
    a[1] = bf2f(hu.y) + bb1 + a01[1];
    a[2] = bf2f(hu.z) + bb2 + a23[0];
    a[3] = bf2f(hu.w) + bb3 + a23[1];
    float sum = 0.f, sq = 0.f;
#pragma unroll
    for (int j = 0; j < 4; ++j) {
        float ex = __expf(-a[j]);
        a[j] = a[j] * __builtin_amdgcn_rcpf(1.f + ex);
        sum += a[j]; sq += a[j] * a[j];
    }
#pragma unroll
    for (int off = 32; off >= 1; off >>= 1) {
        sum += __shfl_xor(sum, off, 64);
        sq  += __shfl_xor(sq,  off, 64);
    }
    float mean = sum * (1.0f / 256.0f);
    float var = sq * (1.0f / 256.0f) - mean * mean;
    float rs = rsqrtf(var + LN_EPS);
#pragma unroll
    for (int j = 0; j < 4; ++j) {
        int c = c0 + j * 16;
        out[rowo + c] = (a[j] - mean) * rs * gamma[c] + beta[c];
    }
}

// ---------------------------------------------------------------------------
extern "C" void kernel_launch(void* const* d_in, const int* in_sizes, int n_in,
                              void* d_out, int out_size, void* d_ws, size_t ws_size,
                              hipStream_t stream) {
    const float* x      = (const float*)d_in[0];
    const int*   ei     = (const int*)d_in[1];
    const float* bases  = (const float*)d_in[2];
    const float* coeff  = (const float*)d_in[3];
    const float* w_self = (const float*)d_in[4];
    const float* b_self = (const float*)d_in[5];
    const float* gamma  = (const float*)d_in[6];
    const float* beta   = (const float*)d_in[7];
    float* out = (float*)d_out;

    ushort* BT  = (ushort*)d_ws;                          // 1280*256 bf16 (0.66 MB)
    ushort* xb  = BT + (size_t)1280 * D;                  // N*256 bf16 (51.2 MB)
    ushort* hb  = xb + (size_t)N_NODES * D;               // N*256 bf16 (51.2 MB)
    uchar*  U   = (uchar*)(hb + (size_t)N_NODES * D);     // N*1024 fp8 (102.4 MB)
    int* cntR   = (int*)(U + (size_t)N_NODES * 1024);     // 8N [dst][r] (3.2 MB)
    int* start  = cntR + (size_t)R_REL * N_NODES;         // N+1
    int* cursor = start + N_NODES + 1;                    // N
    int* sumsA  = cursor + N_NODES;                       // 98 (pad 128)
    int* sumsB  = sumsA + 128;                            // 98 (pad 128)
    int2* pairs = (int2*)(sumsB + 128);                   // ETOT int2 (2.56 MB)

    hipMemsetAsync(cntR, 0, (size_t)R_REL * N_NODES * sizeof(int), stream);

    k_prep<<<PREPX_NB + PREPB_NB + COUNT_NB, 256, 0, stream>>>(x, xb, w_self,
                                                               bases, BT, ei, cntR);
    k_scanA<<<SCAN_NB, 256, 0, stream>>>(cntR, start, sumsA);
    k_scanB<<<1, 256, 0, stream>>>(sumsA, sumsB);
    k_scanC<<<(N_NODES + 255) / 256, 256, 0, stream>>>(start, sumsB, cursor);
    k_scatter<<<(ETOT + 255) / 256, 256, 0, stream>>>(ei, cursor, cntR, pairs);
    k_gemm<<<NWG, 256, 0, stream>>>(xb, BT, hb, U);
    k_final<<<N_NODES / 4, 256, 0, stream>>>(out, hb, U, start, pairs, coeff,
                                             b_self, gamma, beta);
}

// Round 16
// 277.552 us; speedup vs baseline: 1.1133x; 1.1133x over previous
//
#include <hip/hip_runtime.h>
#include <hip/hip_bf16.h>

#define N_NODES 100000
#define D 256
#define R_REL 8
#define E_EDGES 40000
#define LN_EPS 1e-5f
#define ETOT (R_REL * E_EDGES)                    // 320000
#define SCAN_CH 1024
#define SCAN_NB ((N_NODES + SCAN_CH - 1) / SCAN_CH)  // 98
#define NROWT ((N_NODES + 127) / 128)             // 782
#define NWG (NROWT * 10)                          // 7820
#define PREPX_NB (N_NODES * D / 8 / 256)          // 12500
#define PREPB_NB 80
#define COUNT_NB ((ETOT + 255) / 256)             // 1250

typedef __attribute__((ext_vector_type(8))) short short8;
typedef __attribute__((ext_vector_type(4))) float f32x4;
typedef __attribute__((ext_vector_type(2))) float f32x2;
typedef unsigned char uchar;

__device__ inline ushort bf16u(float f) {
    __hip_bfloat16 h = __float2bfloat16(f);
    return *reinterpret_cast<ushort*>(&h);
}
__device__ inline float bf2f(ushort u) { return __uint_as_float(((unsigned)u) << 16); }

// ---------------------------------------------------------------------------
// Fused prep: [0, PREPX_NB) x->xb bf16 | [.., +PREPB_NB) BT transpose |
// [.., +COUNT_NB) per-(dst,r) histogram.  All independent.
__global__ __launch_bounds__(256) void k_prep(const float* __restrict__ x,
                                              ushort* __restrict__ xb,
                                              const float* __restrict__ w_self,
                                              const float* __restrict__ bases,
                                              ushort* __restrict__ BT,
                                              const int* __restrict__ ei,
                                              int* __restrict__ cntR) {
    __shared__ float tile[64][65];
    int b = blockIdx.x;
    int t = threadIdx.x;
    if (b < PREPX_NB) {
        size_t idx = (size_t)b * 256 + t;
        const float4* xp = (const float4*)(x + idx * 8);
        float4 f0 = xp[0], f1 = xp[1];
        short8 v;
        v[0] = (short)bf16u(f0.x); v[1] = (short)bf16u(f0.y);
        v[2] = (short)bf16u(f0.z); v[3] = (short)bf16u(f0.w);
        v[4] = (short)bf16u(f1.x); v[5] = (short)bf16u(f1.y);
        v[6] = (short)bf16u(f1.z); v[7] = (short)bf16u(f1.w);
        *(short8*)(xb + idx * 8) = v;
    } else if (b < PREPX_NB + PREPB_NB) {
        int bb = b - PREPX_NB;
        int ot = bb >> 2, dt = bb & 3;
        int o0 = ot * 64, d0 = dt * 64;
        int m = o0 >> 8;                   // 0 = w_self, 1..4 = bases[m-1]
        const float* src = (m == 0) ? w_self : bases + (size_t)(m - 1) * D * D;
        int ol0 = o0 & 255;
        int cl = t & 63, rw = t >> 6;
        for (int i = 0; i < 16; ++i) {
            int dl = i * 4 + rw;
            tile[dl][cl] = src[(size_t)(d0 + dl) * D + ol0 + cl];
        }
        __syncthreads();
        for (int i = 0; i < 16; ++i) {
            int ol = i * 4 + rw;
            BT[(size_t)(o0 + ol) * D + d0 + cl] = bf16u(tile[cl][ol]);
        }
    } else {
        int idx = (b - PREPX_NB - PREPB_NB) * 256 + t;
        if (idx < ETOT) {
            int r = idx / E_EDGES, e = idx % E_EDGES;
            int dst = ei[(r * 2 + 1) * E_EDGES + e];
            atomicAdd(&cntR[(size_t)dst * 8 + r], 1);
        }
    }
}

// ---------------------------------------------------------------------------
// scanA: per-node degree = sum of cntR[node][0..7], then block exclusive scan.
__global__ __launch_bounds__(256) void k_scanA(const int* __restrict__ cntR,
                                               int* __restrict__ start,
                                               int* __restrict__ sumsA) {
    __shared__ int sc[256];
    int t = threadIdx.x;
    int base = blockIdx.x * SCAN_CH + t * 4;
    int v[4];
#pragma unroll
    for (int i = 0; i < 4; ++i) {
        int node = base + i;
        int s = 0;
        if (node < N_NODES) {
            const int4* c = (const int4*)&cntR[(size_t)node * 8];
            int4 a = c[0], b = c[1];
            s = a.x + a.y + a.z + a.w + b.x + b.y + b.z + b.w;
        }
        v[i] = s;
    }
    int ts = v[0] + v[1] + v[2] + v[3];
    sc[t] = ts;
    __syncthreads();
    for (int off = 1; off < 256; off <<= 1) {
        int val = (t >= off) ? sc[t - off] : 0;
        __syncthreads();
        sc[t] += val;
        __syncthreads();
    }
    int excl = sc[t] - ts;
    if (base + 0 < N_NODES) start[base + 0] = excl;
    if (base + 1 < N_NODES) start[base + 1] = excl + v[0];
    if (base + 2 < N_NODES) start[base + 2] = excl + v[0] + v[1];
    if (base + 3 < N_NODES) start[base + 3] = excl + v[0] + v[1] + v[2];
    if (t == 255) sumsA[blockIdx.x] = sc[255];
}

__global__ __launch_bounds__(256) void k_scanB(const int* __restrict__ sumsA,
                                               int* __restrict__ sumsB) {
    __shared__ int sc[256];
    int t = threadIdx.x;
    int i0 = t * 4;
    int v0 = (i0 + 0 < SCAN_NB) ? sumsA[i0 + 0] : 0;
    int v1 = (i0 + 1 < SCAN_NB) ? sumsA[i0 + 1] : 0;
    int v2 = (i0 + 2 < SCAN_NB) ? sumsA[i0 + 2] : 0;
    int v3 = (i0 + 3 < SCAN_NB) ? sumsA[i0 + 3] : 0;
    int ts = v0 + v1 + v2 + v3;
    sc[t] = ts;
    __syncthreads();
    for (int off = 1; off < 256; off <<= 1) {
        int val = (t >= off) ? sc[t - off] : 0;
        __syncthreads();
        sc[t] += val;
        __syncthreads();
    }
    int excl = sc[t] - ts;
    if (i0 + 0 < SCAN_NB) sumsB[i0 + 0] = excl;
    if (i0 + 1 < SCAN_NB) sumsB[i0 + 1] = excl + v0;
    if (i0 + 2 < SCAN_NB) sumsB[i0 + 2] = excl + v0 + v1;
    if (i0 + 3 < SCAN_NB) sumsB[i0 + 3] = excl + v0 + v1 + v2;
}

__global__ __launch_bounds__(256) void k_scanC(int* __restrict__ start,
                                               const int* __restrict__ sumsB,
                                               int* __restrict__ cursor) {
    int idx = blockIdx.x * blockDim.x + threadIdx.x;
    if (idx < N_NODES) {
        int v = start[idx] + sumsB[idx / SCAN_CH];
        start[idx] = v;
        cursor[idx] = v;
    }
    if (idx == 0) start[N_NODES] = ETOT;
}

// pairs[pos] = {(r<<20)|src, f32 bits of 1/(64*deg_{r,dst})}
__global__ void k_scatter(const int* __restrict__ ei, int* __restrict__ cursor,
                          const int* __restrict__ cntR, int2* __restrict__ pairs) {
    int idx = blockIdx.x * blockDim.x + threadIdx.x;
    if (idx >= ETOT) return;
    int r = idx / E_EDGES, e = idx % E_EDGES;
    int src = ei[r * 2 * E_EDGES + e];
    int dst = ei[(r * 2 + 1) * E_EDGES + e];
    int pos = atomicAdd(&cursor[dst], 1);
    float invd = __builtin_amdgcn_rcpf((float)cntR[(size_t)dst * 8 + r]) * 0.015625f;
    pairs[pos] = make_int2((r << 20) | src, __float_as_int(invd));
}

// ---------------------------------------------------------------------------
// [hb | U] = xb @ BT^T.  128x128 tile, BK=64.
// A: LDS double-buffer via global_load_lds (XOR swizzle).  B: DIRECT from
// global (BT is 0.66 MB, L2/L1-resident) into a register double-buffer,
// prefetched one K-step ahead; kt loop fully unrolled so all breg indices
// are compile-time (no scratch).  LDS = 32 KB (As only).
// m204 bijective XCD swizzle + sigma output layout (unchanged from R12).
__global__ __launch_bounds__(256, 2) void k_gemm(const ushort* __restrict__ xb,
                                                 const ushort* __restrict__ BT,
                                                 ushort* __restrict__ hb,
                                                 uchar* __restrict__ U) {
    __shared__ ushort As[2][128 * 64];     // 2 x 16 KB
    int t = threadIdx.x;

    const int q = NWG / 8, r8 = NWG % 8;
    int dd = blockIdx.x;
    int xcd = dd & 7, slot = dd >> 3;
    int wgid = (xcd < r8 ? xcd * (q + 1) : r8 * (q + 1) + (xcd - r8) * q) + slot;
    int rowtile = wgid / 10, pass = wgid % 10;
    int row0 = rowtile * 128;

    int l = t & 63, w = t >> 6;
    int wr = w >> 1, wc = w & 1;           // 2 x 2 wave grid
    int lr = l & 15, lg = l >> 4;

    auto stageA = [&](int buf, int kt) {
#pragma unroll
        for (int p = 0; p < 4; ++p) {
            int o = p * 4096 + t * 16;
            int rowA = o >> 7;
            int colb = (o & 127) ^ ((rowA & 7) << 4);
            int srcrow = min(row0 + rowA, N_NODES - 1);
            const char* gp = (const char*)xb + ((size_t)srcrow * D + kt * 64) * 2 + colb;
            char* lp = (char*)&As[buf][0] + p * 4096 + (t >> 6) * 1024;  // wave-uniform
            __builtin_amdgcn_global_load_lds(
                (const __attribute__((address_space(1))) void*)gp,
                (__attribute__((address_space(3))) void*)lp, 16, 0, 0);
        }
    };

    // B fragment base: col = pass*128 + wc*64 + ni*16 + lr, elems [kt*64+kk*32+lg*8 ..+8)
    const ushort* Bbase = BT + (size_t)(pass * 128 + wc * 64 + lr) * D + lg * 8;
    short8 breg[2][8];                     // [kt&1][kk*4+ni], all indices static
    auto loadB = [&](int pb, int kt) {
#pragma unroll
        for (int kk = 0; kk < 2; ++kk)
#pragma unroll
            for (int ni = 0; ni < 4; ++ni)
                breg[pb][kk * 4 + ni] = *(const short8*)(Bbase +
                    (size_t)ni * 16 * D + kt * 64 + kk * 32);
    };

    f32x4 acc[4][4] = {};                  // [mi][ni]
    stageA(0, 0);
    loadB(0, 0);
#pragma unroll
    for (int kt = 0; kt < 4; ++kt) {
        __syncthreads();                   // As[kt&1] ready; prior reads done
        if (kt < 3) { stageA((kt & 1) ^ 1, kt + 1); loadB((kt & 1) ^ 1, kt + 1); }
#pragma unroll
        for (int kk = 0; kk < 2; ++kk) {
            int kb = kk * 64 + lg * 16;
            short8 a[4];
#pragma unroll
            for (int mi = 0; mi < 4; ++mi) {
                int row = wr * 64 + mi * 16 + lr;
                a[mi] = *(const short8*)((const char*)&As[kt & 1][0] +
                         row * 128 + (kb ^ ((row & 7) << 4)));
            }
#pragma unroll
            for (int mi = 0; mi < 4; ++mi)
#pragma unroll
                for (int ni = 0; ni < 4; ++ni)
                    acc[mi][ni] = __builtin_amdgcn_mfma_f32_16x16x32_bf16(
                        a[mi], breg[kt & 1][kk * 4 + ni], acc[mi][ni], 0, 0, 0);
        }
    }

    // ---- epilogue (sigma layout; node = row0 + wr*64 + mi*16 + lg*4 + j)
    if (pass < 2) {
        int qbase = pass * 128 + wc * 64 + lr * 4;
#pragma unroll
        for (int mi = 0; mi < 4; ++mi)
#pragma unroll
            for (int j = 0; j < 4; ++j) {
                int node = row0 + wr * 64 + mi * 16 + lg * 4 + j;
                if (node < N_NODES) {
                    ushort4 v4;
                    v4.x = bf16u(acc[mi][0][j]);
                    v4.y = bf16u(acc[mi][1][j]);
                    v4.z = bf16u(acc[mi][2][j]);
                    v4.w = bf16u(acc[mi][3][j]);
                    *(ushort4*)&hb[(size_t)node * D + qbase] = v4;
                }
            }
    } else {
        int pl = pass - 2;
        int qbase = (pl >> 1) * 256 + (pl & 1) * 128 + wc * 64 + lr * 4;
#pragma unroll
        for (int mi = 0; mi < 4; ++mi)
#pragma unroll
            for (int j = 0; j < 4; ++j) {
                int node = row0 + wr * 64 + mi * 16 + lg * 4 + j;
                if (node < N_NODES) {
                    unsigned d = __builtin_amdgcn_cvt_pk_fp8_f32(
                        acc[mi][0][j] * 64.0f, acc[mi][1][j] * 64.0f, 0, false);
                    d = __builtin_amdgcn_cvt_pk_fp8_f32(
                        acc[mi][2][j] * 64.0f, acc[mi][3][j] * 64.0f, d, true);
                    *(unsigned*)&U[(size_t)node * 1024 + qbase] = d;
                }
            }
    }
}

// ---------------------------------------------------------------------------
// Per dst node (one wave each). 2-edge unrolled gather (8 U-dwords in flight),
// packed fp8 decode + pk_fma accumulate, hoisted tail loads, fast SiLU.
__global__ __launch_bounds__(256) void k_final(float* __restrict__ out,
                                               const ushort* __restrict__ hb,
                                               const uchar* __restrict__ U,
                                               const int* __restrict__ start,
                                               const int2* __restrict__ pairs,
                                               const float* __restrict__ coeff,
                                               const float* __restrict__ bias,
                                               const float* __restrict__ gamma,
                                               const float* __restrict__ beta) {
    __shared__ float cf[32];
    int t = threadIdx.x;
    if (t < 32) cf[t] = coeff[t];
    __syncthreads();
    int lane = t & 63, w = t >> 6;
    int n = blockIdx.x * 4 + w;
    int s = start[n], e = start[n + 1];

    // hoisted tail loads (latency hides under the gather)
    int c0 = (lane >> 4) * 64 + (lane & 15);
    size_t rowo = (size_t)n * D;
    ushort4 hu = *(const ushort4*)&hb[rowo + lane * 4];
    float bb0 = bias[c0], bb1 = bias[c0 + 16], bb2 = bias[c0 + 32], bb3 = bias[c0 + 48];

    f32x2 a01 = {0.f, 0.f}, a23 = {0.f, 0.f};
    const uchar* Ul = U + lane * 4;
    int p = s;
    for (; p + 1 < e; p += 2) {
        int2 cA = pairs[p], cB = pairs[p + 1];
        const uchar* upA = Ul + ((size_t)(cA.x & 0xFFFFF) << 10);
        const uchar* upB = Ul + ((size_t)(cB.x & 0xFFFFF) << 10);
        unsigned vA0 = *(const unsigned*)(upA);
        unsigned vA1 = *(const unsigned*)(upA + 256);
        unsigned vA2 = *(const unsigned*)(upA + 512);
        unsigned vA3 = *(const unsigned*)(upA + 768);
        unsigned vB0 = *(const unsigned*)(upB);
        unsigned vB1 = *(const unsigned*)(upB + 256);
        unsigned vB2 = *(const unsigned*)(upB + 512);
        unsigned vB3 = *(const unsigned*)(upB + 768);
        float invA = __int_as_float(cA.y);
        float invB = __int_as_float(cB.y);
        const float* wvA = &cf[(cA.x >> 20) * 4];
        const float* wvB = &cf[(cB.x >> 20) * 4];
        f32x2 wp;
        float ww;
        ww = wvA[0] * invA; wp[0] = ww; wp[1] = ww;
        a01 += wp * __builtin_amdgcn_cvt_pk_f32_fp8(vA0, false);
        a23 += wp * __builtin_amdgcn_cvt_pk_f32_fp8(vA0, true);
        ww = wvA[1] * invA; wp[0] = ww; wp[1] = ww;
        a01 += wp * __builtin_amdgcn_cvt_pk_f32_fp8(vA1, false);
        a23 += wp * __builtin_amdgcn_cvt_pk_f32_fp8(vA1, true);
        ww = wvA[2] * invA; wp[0] = ww; wp[1] = ww;
        a01 += wp * __builtin_amdgcn_cvt_pk_f32_fp8(vA2, false);
        a23 += wp * __builtin_amdgcn_cvt_pk_f32_fp8(vA2, true);
        ww = wvA[3] * invA; wp[0] = ww; wp[1] = ww;
        a01 += wp * __builtin_amdgcn_cvt_pk_f32_fp8(vA3, false);
        a23 += wp * __builtin_amdgcn_cvt_pk_f32_fp8(vA3, true);
        ww = wvB[0] * invB; wp[0] = ww; wp[1] = ww;
        a01 += wp * __builtin_amdgcn_cvt_pk_f32_fp8(vB0, false);
        a23 += wp * __builtin_amdgcn_cvt_pk_f32_fp8(vB0, true);
        ww = wvB[1] * invB; wp[0] = ww; wp[1] = ww;
        a01 += wp * __builtin_amdgcn_cvt_pk_f32_fp8(vB1, false);
        a23 += wp * __builtin_amdgcn_cvt_pk_f32_fp8(vB1, true);
        ww = wvB[2] * invB; wp[0] = ww; wp[1] = ww;
        a01 += wp * __builtin_amdgcn_cvt_pk_f32_fp8(vB2, false);
        a23 += wp * __builtin_amdgcn_cvt_pk_f32_fp8(vB2, true);
        ww = wvB[3] * invB; wp[0] = ww; wp[1] = ww;
        a01 += wp * __builtin_amdgcn_cvt_pk_f32_fp8(vB3, false);
        a23 += wp * __builtin_amdgcn_cvt_pk_f32_fp8(vB3, true);
    }
    if (p < e) {
        int2 cA = pairs[p];
        const uchar* upA = Ul + ((size_t)(cA.x & 0xFFFFF) << 10);
        unsigned vA0 = *(const unsigned*)(upA);
        unsigned vA1 = *(const unsigned*)(upA + 256);
        unsigned vA2 = *(const unsigned*)(upA + 512);
        unsigned vA3 = *(const unsigned*)(upA + 768);
        float invA = __int_as_float(cA.y);
        const float* wvA = &cf[(cA.x >> 20) * 4];
        f32x2 wp;
        float ww;
        ww = wvA[0] * invA; wp[0] = ww; wp[1] = ww;
        a01 += wp * __builtin_amdgcn_cvt_pk_f32_fp8(vA0, false);
        a23 += wp * __builtin_amdgcn_cvt_pk_f32_fp8(vA0, true);
        ww = wvA[1] * invA; wp[0] = ww; wp[1] = ww;
        a01 += wp * __builtin_amdgcn_cvt_pk_f32_fp8(vA1, false);
        a23 += wp * __builtin_amdgcn_cvt_pk_f32_fp8(vA1, true);
        ww = wvA[2] * invA; wp[0] = ww; wp[1] = ww;
        a01 += wp * __builtin_amdgcn_cvt_pk_f32_fp8(vA2, false);
        a23 += wp * __builtin_amdgcn_cvt_pk_f32_fp8(vA2, true);
        ww = wvA[3] * invA; wp[0] = ww; wp[1] = ww;
        a01 += wp * __builtin_amdgcn_cvt_pk_f32_fp8(vA3, false);
        a23 += wp * __builtin_amdgcn_cvt_pk_f32_fp8(vA3, true);
    }

    float a[4];
    a[0] = bf2f(hu.x) + bb0 + a01[0];
    a[1] = bf2f(hu.y) + bb1 + a01[1];
    a[2] = bf2f(hu.z) + bb2 + a23[0];
    a[3] = bf2f(hu.w) + bb3 + a23[1];
    float sum = 0.f, sq = 0.f;
#pragma unroll
    for (int j = 0; j < 4; ++j) {
        float ex = __expf(-a[j]);
        a[j] = a[j] * __builtin_amdgcn_rcpf(1.f + ex);
        sum += a[j]; sq += a[j] * a[j];
    }
#pragma unroll
    for (int off = 32; off >= 1; off >>= 1) {
        sum += __shfl_xor(sum, off, 64);
        sq  += __shfl_xor(sq,  off, 64);
    }
    float mean = sum * (1.0f / 256.0f);
    float var = sq * (1.0f / 256.0f) - mean * mean;
    float rs = rsqrtf(var + LN_EPS);
#pragma unroll
    for (int j = 0; j < 4; ++j) {
        int c = c0 + j * 16;
        out[rowo + c] = (a[j] - mean) * rs * gamma[c] + beta[c];
    }
}

// ---------------------------------------------------------------------------
extern "C" void kernel_launch(void* const* d_in, const int* in_sizes, int n_in,
                              void* d_out, int out_size, void* d_ws, size_t ws_size,
                              hipStream_t stream) {
    const float* x      = (const float*)d_in[0];
    const int*   ei     = (const int*)d_in[1];
    const float* bases  = (const float*)d_in[2];
    const float* coeff  = (const float*)d_in[3];
    const float* w_self = (const float*)d_in[4];
    const float* b_self = (const float*)d_in[5];
    const float* gamma  = (const float*)d_in[6];
    const float* beta   = (const float*)d_in[7];
    float* out = (float*)d_out;

    ushort* BT  = (ushort*)d_ws;                          // 1280*256 bf16 (0.66 MB)
    ushort* xb  = BT + (size_t)1280 * D;                  // N*256 bf16 (51.2 MB)
    ushort* hb  = xb + (size_t)N_NODES * D;               // N*256 bf16 (51.2 MB)
    uchar*  U   = (uchar*)(hb + (size_t)N_NODES * D);     // N*1024 fp8 (102.4 MB)
    int* cntR   = (int*)(U + (size_t)N_NODES * 1024);     // 8N [dst][r] (3.2 MB)
    int* start  = cntR + (size_t)R_REL * N_NODES;         // N+1
    int* cursor = start + N_NODES + 1;                    // N
    int* sumsA  = cursor + N_NODES;                       // 98 (pad 128)
    int* sumsB  = sumsA + 128;                            // 98 (pad 128)
    int2* pairs = (int2*)(sumsB + 128);                   // ETOT int2 (2.56 MB)

    hipMemsetAsync(cntR, 0, (size_t)R_REL * N_NODES * sizeof(int), stream);

    k_prep<<<PREPX_NB + PREPB_NB + COUNT_NB, 256, 0, stream>>>(x, xb, w_self,
                                                               bases, BT, ei, cntR);
    k_scanA<<<SCAN_NB, 256, 0, stream>>>(cntR, start, sumsA);
    k_scanB<<<1, 256, 0, stream>>>(sumsA, sumsB);
    k_scanC<<<(N_NODES + 255) / 256, 256, 0, stream>>>(start, sumsB, cursor);
    k_scatter<<<(ETOT + 255) / 256, 256, 0, stream>>>(ei, cursor, cntR, pairs);
    k_gemm<<<NWG, 256, 0, stream>>>(xb, BT, hb, U);
    k_final<<<N_NODES / 4, 256, 0, stream>>>(out, hb, U, start, pairs, coeff,
                                             b_self, gamma, beta);
}

// Round 17
// 230.321 us; speedup vs baseline: 1.3415x; 1.2051x over previous
//
#include <hip/hip_runtime.h>
#include <hip/hip_bf16.h>

#define N_NODES 100000
#define D 256
#define R_REL 8
#define E_EDGES 40000
#define LN_EPS 1e-5f
#define ETOT (R_REL * E_EDGES)                    // 320000
#define SCAN_CH 1024
#define SCAN_NB ((N_NODES + SCAN_CH - 1) / SCAN_CH)  // 98
#define NROWT ((N_NODES + 127) / 128)             // 782
#define NWG (NROWT * 10)                          // 7820
#define PREPX_NB (N_NODES * D / 8 / 256)          // 12500
#define PREPB_NB 80
#define COUNT_NB ((ETOT + 255) / 256)             // 1250

typedef __attribute__((ext_vector_type(8))) short short8;
typedef __attribute__((ext_vector_type(4))) float f32x4;
typedef __attribute__((ext_vector_type(2))) float f32x2;
typedef unsigned char uchar;

__device__ inline ushort bf16u(float f) {
    __hip_bfloat16 h = __float2bfloat16(f);
    return *reinterpret_cast<ushort*>(&h);
}
__device__ inline float bf2f(ushort u) { return __uint_as_float(((unsigned)u) << 16); }

// ---------------------------------------------------------------------------
// Fused prep: [0, PREPX_NB) x->xb bf16 | [.., +PREPB_NB) BT transpose |
// [.., +COUNT_NB) per-(dst,r) histogram.  All independent.
__global__ __launch_bounds__(256) void k_prep(const float* __restrict__ x,
                                              ushort* __restrict__ xb,
                                              const float* __restrict__ w_self,
                                              const float* __restrict__ bases,
                                              ushort* __restrict__ BT,
                                              const int* __restrict__ ei,
                                              int* __restrict__ cntR) {
    __shared__ float tile[64][65];
    int b = blockIdx.x;
    int t = threadIdx.x;
    if (b < PREPX_NB) {
        size_t idx = (size_t)b * 256 + t;
        const float4* xp = (const float4*)(x + idx * 8);
        float4 f0 = xp[0], f1 = xp[1];
        short8 v;
        v[0] = (short)bf16u(f0.x); v[1] = (short)bf16u(f0.y);
        v[2] = (short)bf16u(f0.z); v[3] = (short)bf16u(f0.w);
        v[4] = (short)bf16u(f1.x); v[5] = (short)bf16u(f1.y);
        v[6] = (short)bf16u(f1.z); v[7] = (short)bf16u(f1.w);
        *(short8*)(xb + idx * 8) = v;
    } else if (b < PREPX_NB + PREPB_NB) {
        int bb = b - PREPX_NB;
        int ot = bb >> 2, dt = bb & 3;
        int o0 = ot * 64, d0 = dt * 64;
        int m = o0 >> 8;                   // 0 = w_self, 1..4 = bases[m-1]
        const float* src = (m == 0) ? w_self : bases + (size_t)(m - 1) * D * D;
        int ol0 = o0 & 255;
        int cl = t & 63, rw = t >> 6;
        for (int i = 0; i < 16; ++i) {
            int dl = i * 4 + rw;
            tile[dl][cl] = src[(size_t)(d0 + dl) * D + ol0 + cl];
        }
        __syncthreads();
        for (int i = 0; i < 16; ++i) {
            int ol = i * 4 + rw;
            BT[(size_t)(o0 + ol) * D + d0 + cl] = bf16u(tile[cl][ol]);
        }
    } else {
        int idx = (b - PREPX_NB - PREPB_NB) * 256 + t;
        if (idx < ETOT) {
            int r = idx / E_EDGES, e = idx % E_EDGES;
            int dst = ei[(r * 2 + 1) * E_EDGES + e];
            atomicAdd(&cntR[(size_t)dst * 8 + r], 1);
        }
    }
}

// ---------------------------------------------------------------------------
// scanA: per-node degree = sum of cntR[node][0..7], then block exclusive scan.
__global__ __launch_bounds__(256) void k_scanA(const int* __restrict__ cntR,
                                               int* __restrict__ start,
                                               int* __restrict__ sumsA) {
    __shared__ int sc[256];
    int t = threadIdx.x;
    int base = blockIdx.x * SCAN_CH + t * 4;
    int v[4];
#pragma unroll
    for (int i = 0; i < 4; ++i) {
        int node = base + i;
        int s = 0;
        if (node < N_NODES) {
            const int4* c = (const int4*)&cntR[(size_t)node * 8];
            int4 a = c[0], b = c[1];
            s = a.x + a.y + a.z + a.w + b.x + b.y + b.z + b.w;
        }
        v[i] = s;
    }
    int ts = v[0] + v[1] + v[2] + v[3];
    sc[t] = ts;
    __syncthreads();
    for (int off = 1; off < 256; off <<= 1) {
        int val = (t >= off) ? sc[t - off] : 0;
        __syncthreads();
        sc[t] += val;
        __syncthreads();
    }
    int excl = sc[t] - ts;
    if (base + 0 < N_NODES) start[base + 0] = excl;
    if (base + 1 < N_NODES) start[base + 1] = excl + v[0];
    if (base + 2 < N_NODES) start[base + 2] = excl + v[0] + v[1];
    if (base + 3 < N_NODES) start[base + 3] = excl + v[0] + v[1] + v[2];
    if (t == 255) sumsA[blockIdx.x] = sc[255];
}

__global__ __launch_bounds__(256) void k_scanB(const int* __restrict__ sumsA,
                                               int* __restrict__ sumsB) {
    __shared__ int sc[256];
    int t = threadIdx.x;
    int i0 = t * 4;
    int v0 = (i0 + 0 < SCAN_NB) ? sumsA[i0 + 0] : 0;
    int v1 = (i0 + 1 < SCAN_NB) ? sumsA[i0 + 1] : 0;
    int v2 = (i0 + 2 < SCAN_NB) ? sumsA[i0 + 2] : 0;
    int v3 = (i0 + 3 < SCAN_NB) ? sumsA[i0 + 3] : 0;
    int ts = v0 + v1 + v2 + v3;
    sc[t] = ts;
    __syncthreads();
    for (int off = 1; off < 256; off <<= 1) {
        int val = (t >= off) ? sc[t - off] : 0;
        __syncthreads();
        sc[t] += val;
        __syncthreads();
    }
    int excl = sc[t] - ts;
    if (i0 + 0 < SCAN_NB) sumsB[i0 + 0] = excl;
    if (i0 + 1 < SCAN_NB) sumsB[i0 + 1] = excl + v0;
    if (i0 + 2 < SCAN_NB) sumsB[i0 + 2] = excl + v0 + v1;
    if (i0 + 3 < SCAN_NB) sumsB[i0 + 3] = excl + v0 + v1 + v2;
}

__global__ __launch_bounds__(256) void k_scanC(int* __restrict__ start,
                                               const int* __restrict__ sumsB,
                                               int* __restrict__ cursor) {
    int idx = blockIdx.x * blockDim.x + threadIdx.x;
    if (idx < N_NODES) {
        int v = start[idx] + sumsB[idx / SCAN_CH];
        start[idx] = v;
        cursor[idx] = v;
    }
    if (idx == 0) start[N_NODES] = ETOT;
}

// pairs[pos] = {(r<<20)|src, f32 bits of 1/(64*deg_{r,dst})}
__global__ void k_scatter(const int* __restrict__ ei, int* __restrict__ cursor,
                          const int* __restrict__ cntR, int2* __restrict__ pairs) {
    int idx = blockIdx.x * blockDim.x + threadIdx.x;
    if (idx >= ETOT) return;
    int r = idx / E_EDGES, e = idx % E_EDGES;
    int src = ei[r * 2 * E_EDGES + e];
    int dst = ei[(r * 2 + 1) * E_EDGES + e];
    int pos = atomicAdd(&cursor[dst], 1);
    float invd = __builtin_amdgcn_rcpf((float)cntR[(size_t)dst * 8 + r]) * 0.015625f;
    pairs[pos] = make_int2((r << 20) | src, __float_as_int(invd));
}

// ---------------------------------------------------------------------------
// [hb | U] = xb @ BT^T.  128x128 tile, BK=64, staging via global_load_lds,
// m204 bijective XCD swizzle, sigma output layout (R14 data path) with a
// COUNTED-VMCNT 2-deep pipeline (T3/T4): raw s_barrier + s_waitcnt vmcnt(8)
// in the main loop -- the stage for kt+1 stays in flight across the barrier.
__global__ __launch_bounds__(256, 2) void k_gemm(const ushort* __restrict__ xb,
                                                 const ushort* __restrict__ BT,
                                                 ushort* __restrict__ hb,
                                                 uchar* __restrict__ U) {
    __shared__ ushort As[2][128 * 64];     // 2 x 16 KB
    __shared__ ushort Bs[2][128 * 64];     // 2 x 16 KB
    int t = threadIdx.x;

    const int q = NWG / 8, r8 = NWG % 8;
    int dd = blockIdx.x;
    int xcd = dd & 7, slot = dd >> 3;
    int wgid = (xcd < r8 ? xcd * (q + 1) : r8 * (q + 1) + (xcd - r8) * q) + slot;
    int rowtile = wgid / 10, pass = wgid % 10;
    int row0 = rowtile * 128;

    int l = t & 63, w = t >> 6;
    int wr = w >> 1, wc = w & 1;           // 2 x 2 wave grid
    int lr = l & 15, lg = l >> 4;

    auto stageA = [&](int buf, int kt) {
#pragma unroll
        for (int p = 0; p < 4; ++p) {
            int o = p * 4096 + t * 16;
            int rowA = o >> 7;
            int colb = (o & 127) ^ ((rowA & 7) << 4);
            int srcrow = min(row0 + rowA, N_NODES - 1);
            const char* gp = (const char*)xb + ((size_t)srcrow * D + kt * 64) * 2 + colb;
            char* lp = (char*)&As[buf][0] + p * 4096 + (t >> 6) * 1024;  // wave-uniform
            __builtin_amdgcn_global_load_lds(
                (const __attribute__((address_space(1))) void*)gp,
                (__attribute__((address_space(3))) void*)lp, 16, 0, 0);
        }
    };
    auto stageB = [&](int buf, int kt) {
#pragma unroll
        for (int p = 0; p < 4; ++p) {
            int o = p * 4096 + t * 16;
            int rowB = o >> 7;
            int colb = (o & 127) ^ ((rowB & 7) << 4);
            const char* gp = (const char*)BT +
                ((size_t)(pass * 128 + rowB) * D + kt * 64) * 2 + colb;
            char* lp = (char*)&Bs[buf][0] + p * 4096 + (t >> 6) * 1024;
            __builtin_amdgcn_global_load_lds(
                (const __attribute__((address_space(1))) void*)gp,
                (__attribute__((address_space(3))) void*)lp, 16, 0, 0);
        }
    };

    f32x4 acc[4][4] = {};                  // [mi][ni]
    stageA(0, 0); stageB(0, 0);            // 8 loads (oldest)
    stageA(1, 1); stageB(1, 1);            // 8 more   (16 in flight)
#pragma unroll
    for (int kt = 0; kt < 4; ++kt) {
        int buf = kt & 1;
        // stage(kt) complete; stage(kt+1)'s 8 loads stay in flight
        if (kt < 3) asm volatile("s_waitcnt vmcnt(8)" ::: "memory");
        else        asm volatile("s_waitcnt vmcnt(0)" ::: "memory");
        __builtin_amdgcn_s_barrier();
        // read all fragments for this K-step
        short8 a[2][4], b[2][4];
#pragma unroll
        for (int kk = 0; kk < 2; ++kk) {
            int kb = kk * 64 + lg * 16;
#pragma unroll
            for (int mi = 0; mi < 4; ++mi) {
                int row = wr * 64 + mi * 16 + lr;
                a[kk][mi] = *(const short8*)((const char*)&As[buf][0] +
                             row * 128 + (kb ^ ((row & 7) << 4)));
            }
#pragma unroll
            for (int ni = 0; ni < 4; ++ni) {
                int rb = wc * 64 + ni * 16 + lr;
                b[kk][ni] = *(const short8*)((const char*)&Bs[buf][0] +
                             rb * 128 + (kb ^ ((rb & 7) << 4)));
            }
        }
        // own reads landed; barrier so every wave's reads of buf are done
        asm volatile("s_waitcnt lgkmcnt(0)" ::: "memory");
        __builtin_amdgcn_s_barrier();
        // refill the freed buffer (kt+2) while MFMAs run
        if (kt < 2) { stageA(buf, kt + 2); stageB(buf, kt + 2); }
#pragma unroll
        for (int kk = 0; kk < 2; ++kk)
#pragma unroll
            for (int mi = 0; mi < 4; ++mi)
#pragma unroll
                for (int ni = 0; ni < 4; ++ni)
                    acc[mi][ni] = __builtin_amdgcn_mfma_f32_16x16x32_bf16(
                        a[kk][mi], b[kk][ni], acc[mi][ni], 0, 0, 0);
    }

    // ---- epilogue (sigma layout; node = row0 + wr*64 + mi*16 + lg*4 + j)
    if (pass < 2) {
        int qbase = pass * 128 + wc * 64 + lr * 4;
#pragma unroll
        for (int mi = 0; mi < 4; ++mi)
#pragma unroll
            for (int j = 0; j < 4; ++j) {
                int node = row0 + wr * 64 + mi * 16 + lg * 4 + j;
                if (node < N_NODES) {
                    ushort4 v4;
                    v4.x = bf16u(acc[mi][0][j]);
                    v4.y = bf16u(acc[mi][1][j]);
                    v4.z = bf16u(acc[mi][2][j]);
                    v4.w = bf16u(acc[mi][3][j]);
                    *(ushort4*)&hb[(size_t)node * D + qbase] = v4;
                }
            }
    } else {
        int pl = pass - 2;
        int qbase = (pl >> 1) * 256 + (pl & 1) * 128 + wc * 64 + lr * 4;
#pragma unroll
        for (int mi = 0; mi < 4; ++mi)
#pragma unroll
            for (int j = 0; j < 4; ++j) {
                int node = row0 + wr * 64 + mi * 16 + lg * 4 + j;
                if (node < N_NODES) {
                    unsigned d = __builtin_amdgcn_cvt_pk_fp8_f32(
                        acc[mi][0][j] * 64.0f, acc[mi][1][j] * 64.0f, 0, false);
                    d = __builtin_amdgcn_cvt_pk_fp8_f32(
                        acc[mi][2][j] * 64.0f, acc[mi][3][j] * 64.0f, d, true);
                    *(unsigned*)&U[(size_t)node * 1024 + qbase] = d;
                }
            }
    }
}

// ---------------------------------------------------------------------------
// Per dst node (one wave each). 2-edge unrolled gather (8 U-dwords in flight),
// packed fp8 decode + pk_fma accumulate, hoisted tail loads, fast SiLU.
__global__ __launch_bounds__(256) void k_final(float* __restrict__ out,
                                               const ushort* __restrict__ hb,
                                               const uchar* __restrict__ U,
                                               const int* __restrict__ start,
                                               const int2* __restrict__ pairs,
                                               const float* __restrict__ coeff,
                                               const float* __restrict__ bias,
                                               const float* __restrict__ gamma,
                                               const float* __restrict__ beta) {
    __shared__ float cf[32];
    int t = threadIdx.x;
    if (t < 32) cf[t] = coeff[t];
    __syncthreads();
    int lane = t & 63, w = t >> 6;
    int n = blockIdx.x * 4 + w;
    int s = start[n], e = start[n + 1];

    // hoisted tail loads (latency hides under the gather)
    int c0 = (lane >> 4) * 64 + (lane & 15);
    size_t rowo = (size_t)n * D;
    ushort4 hu = *(const ushort4*)&hb[rowo + lane * 4];
    float bb0 = bias[c0], bb1 = bias[c0 + 16], bb2 = bias[c0 + 32], bb3 = bias[c0 + 48];

    f32x2 a01 = {0.f, 0.f}, a23 = {0.f, 0.f};
    const uchar* Ul = U + lane * 4;
    int p = s;
    for (; p + 1 < e; p += 2) {
        int2 cA = pairs[p], cB = pairs[p + 1];
        const uchar* upA = Ul + ((size_t)(cA.x & 0xFFFFF) << 10);
        const uchar* upB = Ul + ((size_t)(cB.x & 0xFFFFF) << 10);
        unsigned vA0 = *(const unsigned*)(upA);
        unsigned vA1 = *(const unsigned*)(upA + 256);
        unsigned vA2 = *(const unsigned*)(upA + 512);
        unsigned vA3 = *(const unsigned*)(upA + 768);
        unsigned vB0 = *(const unsigned*)(upB);
        unsigned vB1 = *(const unsigned*)(upB + 256);
        unsigned vB2 = *(const unsigned*)(upB + 512);
        unsigned vB3 = *(const unsigned*)(upB + 768);
        float invA = __int_as_float(cA.y);
        float invB = __int_as_float(cB.y);
        const float* wvA = &cf[(cA.x >> 20) * 4];
        const float* wvB = &cf[(cB.x >> 20) * 4];
        f32x2 wp;
        float ww;
        ww = wvA[0] * invA; wp[0] = ww; wp[1] = ww;
        a01 += wp * __builtin_amdgcn_cvt_pk_f32_fp8(vA0, false);
        a23 += wp * __builtin_amdgcn_cvt_pk_f32_fp8(vA0, true);
        ww = wvA[1] * invA; wp[0] = ww; wp[1] = ww;
        a01 += wp * __builtin_amdgcn_cvt_pk_f32_fp8(vA1, false);
        a23 += wp * __builtin_amdgcn_cvt_pk_f32_fp8(vA1, true);
        ww = wvA[2] * invA; wp[0] = ww; wp[1] = ww;
        a01 += wp * __builtin_amdgcn_cvt_pk_f32_fp8(vA2, false);
        a23 += wp * __builtin_amdgcn_cvt_pk_f32_fp8(vA2, true);
        ww = wvA[3] * invA; wp[0] = ww; wp[1] = ww;
        a01 += wp * __builtin_amdgcn_cvt_pk_f32_fp8(vA3, false);
        a23 += wp * __builtin_amdgcn_cvt_pk_f32_fp8(vA3, true);
        ww = wvB[0] * invB; wp[0] = ww; wp[1] = ww;
        a01 += wp * __builtin_amdgcn_cvt_pk_f32_fp8(vB0, false);
        a23 += wp * __builtin_amdgcn_cvt_pk_f32_fp8(vB0, true);
        ww = wvB[1] * invB; wp[0] = ww; wp[1] = ww;
        a01 += wp * __builtin_amdgcn_cvt_pk_f32_fp8(vB1, false);
        a23 += wp * __builtin_amdgcn_cvt_pk_f32_fp8(vB1, true);
        ww = wvB[2] * invB; wp[0] = ww; wp[1] = ww;
        a01 += wp * __builtin_amdgcn_cvt_pk_f32_fp8(vB2, false);
        a23 += wp * __builtin_amdgcn_cvt_pk_f32_fp8(vB2, true);
        ww = wvB[3] * invB; wp[0] = ww; wp[1] = ww;
        a01 += wp * __builtin_amdgcn_cvt_pk_f32_fp8(vB3, false);
        a23 += wp * __builtin_amdgcn_cvt_pk_f32_fp8(vB3, true);
    }
    if (p < e) {
        int2 cA = pairs[p];
        const uchar* upA = Ul + ((size_t)(cA.x & 0xFFFFF) << 10);
        unsigned vA0 = *(const unsigned*)(upA);
        unsigned vA1 = *(const unsigned*)(upA + 256);
        unsigned vA2 = *(const unsigned*)(upA + 512);
        unsigned vA3 = *(const unsigned*)(upA + 768);
        float invA = __int_as_float(cA.y);
        const float* wvA = &cf[(cA.x >> 20) * 4];
        f32x2 wp;
        float ww;
        ww = wvA[0] * invA; wp[0] = ww; wp[1] = ww;
        a01 += wp * __builtin_amdgcn_cvt_pk_f32_fp8(vA0, false);
        a23 += wp * __builtin_amdgcn_cvt_pk_f32_fp8(vA0, true);
        ww = wvA[1] * invA; wp[0] = ww; wp[1] = ww;
        a01 += wp * __builtin_amdgcn_cvt_pk_f32_fp8(vA1, false);
        a23 += wp * __builtin_amdgcn_cvt_pk_f32_fp8(vA1, true);
        ww = wvA[2] * invA; wp[0] = ww; wp[1] = ww;
        a01 += wp * __builtin_amdgcn_cvt_pk_f32_fp8(vA2, false);
        a23 += wp * __builtin_amdgcn_cvt_pk_f32_fp8(vA2, true);
        ww = wvA[3] * invA; wp[0] = ww; wp[1] = ww;
        a01 += wp * __builtin_amdgcn_cvt_pk_f32_fp8(vA3, false);
        a23 += wp * __builtin_amdgcn_cvt_pk_f32_fp8(vA3, true);
    }

    float a[4];
    a[0] = bf2f(hu.x) + bb0 + a01[0];
    a[1] = bf2f(hu.y) + bb1 + a01[1];
    a[2] = bf2f(hu.z) + bb2 + a23[0];
    a[3] = bf2f(hu.w) + bb3 + a23[1];
    float sum = 0.f, sq = 0.f;
#pragma unroll
    for (int j = 0; j < 4; ++j) {
        float ex = __expf(-a[j]);
        a[j] = a[j] * __builtin_amdgcn_rcpf(1.f + ex);
        sum += a[j]; sq += a[j] * a[j];
    }
#pragma unroll
    for (int off = 32; off >= 1; off >>= 1) {
        sum += __shfl_xor(sum, off, 64);
        sq  += __shfl_xor(sq,  off, 64);
    }
    float mean = sum * (1.0f / 256.0f);
    float var = sq * (1.0f / 256.0f) - mean * mean;
    float rs = rsqrtf(var + LN_EPS);
#pragma unroll
    for (int j = 0; j < 4; ++j) {
        int c = c0 + j * 16;
        out[rowo + c] = (a[j] - mean) * rs * gamma[c] + beta[c];
    }
}

// ---------------------------------------------------------------------------
extern "C" void kernel_launch(void* const* d_in, const int* in_sizes, int n_in,
                              void* d_out, int out_size, void* d_ws, size_t ws_size,
                              hipStream_t stream) {
    const float* x      = (const float*)d_in[0];
    const int*   ei     = (const int*)d_in[1];
    const float* bases  = (const float*)d_in[2];
    const float* coeff  = (const float*)d_in[3];
    const float* w_self = (const float*)d_in[4];
    const float* b_self = (const float*)d_in[5];
    const float* gamma  = (const float*)d_in[6];
    const float* beta   = (const float*)d_in[7];
    float* out = (float*)d_out;

    ushort* BT  = (ushort*)d_ws;                          // 1280*256 bf16 (0.66 MB)
    ushort* xb  = BT + (size_t)1280 * D;                  // N*256 bf16 (51.2 MB)
    ushort* hb  = xb + (size_t)N_NODES * D;               // N*256 bf16 (51.2 MB)
    uchar*  U   = (uchar*)(hb + (size_t)N_NODES * D);     // N*1024 fp8 (102.4 MB)
    int* cntR   = (int*)(U + (size_t)N_NODES * 1024);     // 8N [dst][r] (3.2 MB)
    int* start  = cntR + (size_t)R_REL * N_NODES;         // N+1
    int* cursor = start + N_NODES + 1;                    // N
    int* sumsA  = cursor + N_NODES;                       // 98 (pad 128)
    int* sumsB  = sumsA + 128;                            // 98 (pad 128)
    int2* pairs = (int2*)(sumsB + 128);                   // ETOT int2 (2.56 MB)

    hipMemsetAsync(cntR, 0, (size_t)R_REL * N_NODES * sizeof(int), stream);

    k_prep<<<PREPX_NB + PREPB_NB + COUNT_NB, 256, 0, stream>>>(x, xb, w_self,
                                                               bases, BT, ei, cntR);
    k_scanA<<<SCAN_NB, 256, 0, stream>>>(cntR, start, sumsA);
    k_scanB<<<1, 256, 0, stream>>>(sumsA, sumsB);
    k_scanC<<<(N_NODES + 255) / 256, 256, 0, stream>>>(start, sumsB, cursor);
    k_scatter<<<(ETOT + 255) / 256, 256, 0, stream>>>(ei, cursor, cntR, pairs);
    k_gemm<<<NWG, 256, 0, stream>>>(xb, BT, hb, U);
    k_final<<<N_NODES / 4, 256, 0, stream>>>(out, hb, U, start, pairs, coeff,
                                             b_self, gamma, beta);
}

// Round 18
// 230.083 us; speedup vs baseline: 1.3429x; 1.0010x over previous
//
#include <hip/hip_runtime.h>
#include <hip/hip_bf16.h>

#define N_NODES 100000
#define D 256
#define R_REL 8
#define E_EDGES 40000
#define LN_EPS 1e-5f
#define ETOT (R_REL * E_EDGES)                    // 320000
#define SCAN_CH 1024
#define SCAN_NB ((N_NODES + SCAN_CH - 1) / SCAN_CH)  // 98
#define NROWT ((N_NODES + 127) / 128)             // 782
#define NWG (NROWT * 10)                          // 7820
#define PREPX_NB (N_NODES * D / 8 / 256)          // 12500
#define PREPB_NB 80
#define COUNT_NB ((ETOT + 255) / 256)             // 1250

typedef __attribute__((ext_vector_type(8))) short short8;
typedef __attribute__((ext_vector_type(4))) float f32x4;
typedef __attribute__((ext_vector_type(2))) float f32x2;
typedef unsigned char uchar;

__device__ inline ushort bf16u(float f) {
    __hip_bfloat16 h = __float2bfloat16(f);
    return *reinterpret_cast<ushort*>(&h);
}
__device__ inline float bf2f(ushort u) { return __uint_as_float(((unsigned)u) << 16); }

// ---------------------------------------------------------------------------
// Fused prep: [0, PREPX_NB) x->xb bf16 | [.., +PREPB_NB) BT transpose |
// [.., +COUNT_NB) per-(dst,r) histogram.  All independent.
__global__ __launch_bounds__(256) void k_prep(const float* __restrict__ x,
                                              ushort* __restrict__ xb,
                                              const float* __restrict__ w_self,
                                              const float* __restrict__ bases,
                                              ushort* __restrict__ BT,
                                              const int* __restrict__ ei,
                                              int* __restrict__ cntR) {
    __shared__ float tile[64][65];
    int b = blockIdx.x;
    int t = threadIdx.x;
    if (b < PREPX_NB) {
        size_t idx = (size_t)b * 256 + t;
        const float4* xp = (const float4*)(x + idx * 8);
        float4 f0 = xp[0], f1 = xp[1];
        short8 v;
        v[0] = (short)bf16u(f0.x); v[1] = (short)bf16u(f0.y);
        v[2] = (short)bf16u(f0.z); v[3] = (short)bf16u(f0.w);
        v[4] = (short)bf16u(f1.x); v[5] = (short)bf16u(f1.y);
        v[6] = (short)bf16u(f1.z); v[7] = (short)bf16u(f1.w);
        *(short8*)(xb + idx * 8) = v;
    } else if (b < PREPX_NB + PREPB_NB) {
        int bb = b - PREPX_NB;
        int ot = bb >> 2, dt = bb & 3;
        int o0 = ot * 64, d0 = dt * 64;
        int m = o0 >> 8;                   // 0 = w_self, 1..4 = bases[m-1]
        const float* src = (m == 0) ? w_self : bases + (size_t)(m - 1) * D * D;
        int ol0 = o0 & 255;
        int cl = t & 63, rw = t >> 6;
        for (int i = 0; i < 16; ++i) {
            int dl = i * 4 + rw;
            tile[dl][cl] = src[(size_t)(d0 + dl) * D + ol0 + cl];
        }
        __syncthreads();
        for (int i = 0; i < 16; ++i) {
            int ol = i * 4 + rw;
            BT[(size_t)(o0 + ol) * D + d0 + cl] = bf16u(tile[cl][ol]);
        }
    } else {
        int idx = (b - PREPX_NB - PREPB_NB) * 256 + t;
        if (idx < ETOT) {
            int r = idx / E_EDGES, e = idx % E_EDGES;
            int dst = ei[(r * 2 + 1) * E_EDGES + e];
            atomicAdd(&cntR[(size_t)dst * 8 + r], 1);
        }
    }
}

// ---------------------------------------------------------------------------
// scanA: per-node degree = sum of cntR[node][0..7], then block exclusive scan.
__global__ __launch_bounds__(256) void k_scanA(const int* __restrict__ cntR,
                                               int* __restrict__ start,
                                               int* __restrict__ sumsA) {
    __shared__ int sc[256];
    int t = threadIdx.x;
    int base = blockIdx.x * SCAN_CH + t * 4;
    int v[4];
#pragma unroll
    for (int i = 0; i < 4; ++i) {
        int node = base + i;
        int s = 0;
        if (node < N_NODES) {
            const int4* c = (const int4*)&cntR[(size_t)node * 8];
            int4 a = c[0], b = c[1];
            s = a.x + a.y + a.z + a.w + b.x + b.y + b.z + b.w;
        }
        v[i] = s;
    }
    int ts = v[0] + v[1] + v[2] + v[3];
    sc[t] = ts;
    __syncthreads();
    for (int off = 1; off < 256; off <<= 1) {
        int val = (t >= off) ? sc[t - off] : 0;
        __syncthreads();
        sc[t] += val;
        __syncthreads();
    }
    int excl = sc[t] - ts;
    if (base + 0 < N_NODES) start[base + 0] = excl;
    if (base + 1 < N_NODES) start[base + 1] = excl + v[0];
    if (base + 2 < N_NODES) start[base + 2] = excl + v[0] + v[1];
    if (base + 3 < N_NODES) start[base + 3] = excl + v[0] + v[1] + v[2];
    if (t == 255) sumsA[blockIdx.x] = sc[255];
}

// scanC: adds the cross-chunk prefix (computed in-block from sumsA, 98 ints)
// -- replaces the old separate scanB kernel.
__global__ __launch_bounds__(256) void k_scanC(int* __restrict__ start,
                                               const int* __restrict__ sumsA,
                                               int* __restrict__ cursor) {
    __shared__ int pre[128];               // inclusive prefix of sumsA
    int t = threadIdx.x;
    if (t < 128) pre[t] = (t < SCAN_NB) ? sumsA[t] : 0;
    __syncthreads();
    for (int off = 1; off < 128; off <<= 1) {
        int val = 0;
        if (t < 128 && t >= off) val = pre[t - off];
        __syncthreads();
        if (t < 128) pre[t] += val;
        __syncthreads();
    }
    int idx = blockIdx.x * blockDim.x + t;
    if (idx < N_NODES) {
        int chunk = idx / SCAN_CH;
        int add = (chunk == 0) ? 0 : pre[chunk - 1];
        int v = start[idx] + add;
        start[idx] = v;
        cursor[idx] = v;
    }
    if (idx == 0) start[N_NODES] = ETOT;
}

// pairs[pos] = {(r<<20)|src, f32 bits of 1/(64*deg_{r,dst})}
__global__ void k_scatter(const int* __restrict__ ei, int* __restrict__ cursor,
                          const int* __restrict__ cntR, int2* __restrict__ pairs) {
    int idx = blockIdx.x * blockDim.x + threadIdx.x;
    if (idx >= ETOT) return;
    int r = idx / E_EDGES, e = idx % E_EDGES;
    int src = ei[r * 2 * E_EDGES + e];
    int dst = ei[(r * 2 + 1) * E_EDGES + e];
    int pos = atomicAdd(&cursor[dst], 1);
    float invd = __builtin_amdgcn_rcpf((float)cntR[(size_t)dst * 8 + r]) * 0.015625f;
    pairs[pos] = make_int2((r << 20) | src, __float_as_int(invd));
}

// ---------------------------------------------------------------------------
// [hb | U] = xb @ BT^T.  128x128 tile, BK=64, staging via global_load_lds,
// m204 bijective XCD swizzle, sigma output layout, COUNTED-VMCNT 2-deep
// pipeline (R17) + T5 s_setprio around the MFMA cluster.
__global__ __launch_bounds__(256, 2) void k_gemm(const ushort* __restrict__ xb,
                                                 const ushort* __restrict__ BT,
                                                 ushort* __restrict__ hb,
                                                 uchar* __restrict__ U) {
    __shared__ ushort As[2][128 * 64];     // 2 x 16 KB
    __shared__ ushort Bs[2][128 * 64];     // 2 x 16 KB
    int t = threadIdx.x;

    const int q = NWG / 8, r8 = NWG % 8;
    int dd = blockIdx.x;
    int xcd = dd & 7, slot = dd >> 3;
    int wgid = (xcd < r8 ? xcd * (q + 1) : r8 * (q + 1) + (xcd - r8) * q) + slot;
    int rowtile = wgid / 10, pass = wgid % 10;
    int row0 = rowtile * 128;

    int l = t & 63, w = t >> 6;
    int wr = w >> 1, wc = w & 1;           // 2 x 2 wave grid
    int lr = l & 15, lg = l >> 4;

    auto stageA = [&](int buf, int kt) {
#pragma unroll
        for (int p = 0; p < 4; ++p) {
            int o = p * 4096 + t * 16;
            int rowA = o >> 7;
            int colb = (o & 127) ^ ((rowA & 7) << 4);
            int srcrow = min(row0 + rowA, N_NODES - 1);
            const char* gp = (const char*)xb + ((size_t)srcrow * D + kt * 64) * 2 + colb;
            char* lp = (char*)&As[buf][0] + p * 4096 + (t >> 6) * 1024;  // wave-uniform
            __builtin_amdgcn_global_load_lds(
                (const __attribute__((address_space(1))) void*)gp,
                (__attribute__((address_space(3))) void*)lp, 16, 0, 0);
        }
    };
    auto stageB = [&](int buf, int kt) {
#pragma unroll
        for (int p = 0; p < 4; ++p) {
            int o = p * 4096 + t * 16;
            int rowB = o >> 7;
            int colb = (o & 127) ^ ((rowB & 7) << 4);
            const char* gp = (const char*)BT +
                ((size_t)(pass * 128 + rowB) * D + kt * 64) * 2 + colb;
            char* lp = (char*)&Bs[buf][0] + p * 4096 + (t >> 6) * 1024;
            __builtin_amdgcn_global_load_lds(
                (const __attribute__((address_space(1))) void*)gp,
                (__attribute__((address_space(3))) void*)lp, 16, 0, 0);
        }
    };

    f32x4 acc[4][4] = {};                  // [mi][ni]
    stageA(0, 0); stageB(0, 0);            // 8 loads (oldest)
    stageA(1, 1); stageB(1, 1);            // 8 more   (16 in flight)
#pragma unroll
    for (int kt = 0; kt < 4; ++kt) {
        int buf = kt & 1;
        // stage(kt) complete; stage(kt+1)'s 8 loads stay in flight
        if (kt < 3) asm volatile("s_waitcnt vmcnt(8)" ::: "memory");
        else        asm volatile("s_waitcnt vmcnt(0)" ::: "memory");
        __builtin_amdgcn_s_barrier();
        // read all fragments for this K-step
        short8 a[2][4], b[2][4];
#pragma unroll
        for (int kk = 0; kk < 2; ++kk) {
            int kb = kk * 64 + lg * 16;
#pragma unroll
            for (int mi = 0; mi < 4; ++mi) {
                int row = wr * 64 + mi * 16 + lr;
                a[kk][mi] = *(const short8*)((const char*)&As[buf][0] +
                             row * 128 + (kb ^ ((row & 7) << 4)));
            }
#pragma unroll
            for (int ni = 0; ni < 4; ++ni) {
                int rb = wc * 64 + ni * 16 + lr;
                b[kk][ni] = *(const short8*)((const char*)&Bs[buf][0] +
                             rb * 128 + (kb ^ ((rb & 7) << 4)));
            }
        }
        // own reads landed; barrier so every wave's reads of buf are done
        asm volatile("s_waitcnt lgkmcnt(0)" ::: "memory");
        __builtin_amdgcn_s_barrier();
        // refill the freed buffer (kt+2) while MFMAs run
        if (kt < 2) { stageA(buf, kt + 2); stageB(buf, kt + 2); }
        __builtin_amdgcn_s_setprio(1);
#pragma unroll
        for (int kk = 0; kk < 2; ++kk)
#pragma unroll
            for (int mi = 0; mi < 4; ++mi)
#pragma unroll
                for (int ni = 0; ni < 4; ++ni)
                    acc[mi][ni] = __builtin_amdgcn_mfma_f32_16x16x32_bf16(
                        a[kk][mi], b[kk][ni], acc[mi][ni], 0, 0, 0);
        __builtin_amdgcn_s_setprio(0);
    }

    // ---- epilogue (sigma layout; node = row0 + wr*64 + mi*16 + lg*4 + j)
    if (pass < 2) {
        int qbase = pass * 128 + wc * 64 + lr * 4;
#pragma unroll
        for (int mi = 0; mi < 4; ++mi)
#pragma unroll
            for (int j = 0; j < 4; ++j) {
                int node = row0 + wr * 64 + mi * 16 + lg * 4 + j;
                if (node < N_NODES) {
                    ushort4 v4;
                    v4.x = bf16u(acc[mi][0][j]);
                    v4.y = bf16u(acc[mi][1][j]);
                    v4.z = bf16u(acc[mi][2][j]);
                    v4.w = bf16u(acc[mi][3][j]);
                    *(ushort4*)&hb[(size_t)node * D + qbase] = v4;
                }
            }
    } else {
        int pl = pass - 2;
        int qbase = (pl >> 1) * 256 + (pl & 1) * 128 + wc * 64 + lr * 4;
#pragma unroll
        for (int mi = 0; mi < 4; ++mi)
#pragma unroll
            for (int j = 0; j < 4; ++j) {
                int node = row0 + wr * 64 + mi * 16 + lg * 4 + j;
                if (node < N_NODES) {
                    unsigned d = __builtin_amdgcn_cvt_pk_fp8_f32(
                        acc[mi][0][j] * 64.0f, acc[mi][1][j] * 64.0f, 0, false);
                    d = __builtin_amdgcn_cvt_pk_fp8_f32(
                        acc[mi][2][j] * 64.0f, acc[mi][3][j] * 64.0f, d, true);
                    *(unsigned*)&U[(size_t)node * 1024 + qbase] = d;
                }
            }
    }
}

// ---------------------------------------------------------------------------
// Per dst node (one wave each). 4-edge unrolled gather (16 U-dwords in
// flight), packed fp8 decode + pk_fma accumulate, hoisted tail, fast SiLU.
__global__ __launch_bounds__(256) void k_final(float* __restrict__ out,
                                               const ushort* __restrict__ hb,
                                               const uchar* __restrict__ U,
                                               const int* __restrict__ start,
                                               const int2* __restrict__ pairs,
                                               const float* __restrict__ coeff,
                                               const float* __restrict__ bias,
                                               const float* __restrict__ gamma,
                                               const float* __restrict__ beta) {
    __shared__ float cf[32];
    int t = threadIdx.x;
    if (t < 32) cf[t] = coeff[t];
    __syncthreads();
    int lane = t & 63, w = t >> 6;
    int n = blockIdx.x * 4 + w;
    int s = start[n], e = start[n + 1];

    // hoisted tail loads (latency hides under the gather)
    int c0 = (lane >> 4) * 64 + (lane & 15);
    size_t rowo = (size_t)n * D;
    ushort4 hu = *(const ushort4*)&hb[rowo + lane * 4];
    float bb0 = bias[c0], bb1 = bias[c0 + 16], bb2 = bias[c0 + 32], bb3 = bias[c0 + 48];

    f32x2 a01 = {0.f, 0.f}, a23 = {0.f, 0.f};
    const uchar* Ul = U + lane * 4;

    auto edgemath = [&](int2 c, unsigned v0, unsigned v1, unsigned v2, unsigned v3) {
        float inv = __int_as_float(c.y);
        const float* wv = &cf[(c.x >> 20) * 4];
        f32x2 wp;
        float ww;
        ww = wv[0] * inv; wp[0] = ww; wp[1] = ww;
        a01 += wp * __builtin_amdgcn_cvt_pk_f32_fp8(v0, false);
        a23 += wp * __builtin_amdgcn_cvt_pk_f32_fp8(v0, true);
        ww = wv[1] * inv; wp[0] = ww; wp[1] = ww;
        a01 += wp * __builtin_amdgcn_cvt_pk_f32_fp8(v1, false);
        a23 += wp * __builtin_amdgcn_cvt_pk_f32_fp8(v1, true);
        ww = wv[2] * inv; wp[0] = ww; wp[1] = ww;
        a01 += wp * __builtin_amdgcn_cvt_pk_f32_fp8(v2, false);
        a23 += wp * __builtin_amdgcn_cvt_pk_f32_fp8(v2, true);
        ww = wv[3] * inv; wp[0] = ww; wp[1] = ww;
        a01 += wp * __builtin_amdgcn_cvt_pk_f32_fp8(v3, false);
        a23 += wp * __builtin_amdgcn_cvt_pk_f32_fp8(v3, true);
    };

    int p = s;
    for (; p + 3 < e; p += 4) {
        int2 cA = pairs[p], cB = pairs[p + 1], cC = pairs[p + 2], cD = pairs[p + 3];
        const uchar* uA = Ul + ((size_t)(cA.x & 0xFFFFF) << 10);
        const uchar* uB = Ul + ((size_t)(cB.x & 0xFFFFF) << 10);
        const uchar* uC = Ul + ((size_t)(cC.x & 0xFFFFF) << 10);
        const uchar* uD = Ul + ((size_t)(cD.x & 0xFFFFF) << 10);
        unsigned vA0 = *(const unsigned*)(uA);
        unsigned vA1 = *(const unsigned*)(uA + 256);
        unsigned vA2 = *(const unsigned*)(uA + 512);
        unsigned vA3 = *(const unsigned*)(uA + 768);
        unsigned vB0 = *(const unsigned*)(uB);
        unsigned vB1 = *(const unsigned*)(uB + 256);
        unsigned vB2 = *(const unsigned*)(uB + 512);
        unsigned vB3 = *(const unsigned*)(uB + 768);
        unsigned vC0 = *(const unsigned*)(uC);
        unsigned vC1 = *(const unsigned*)(uC + 256);
        unsigned vC2 = *(const unsigned*)(uC + 512);
        unsigned vC3 = *(const unsigned*)(uC + 768);
        unsigned vD0 = *(const unsigned*)(uD);
        unsigned vD1 = *(const unsigned*)(uD + 256);
        unsigned vD2 = *(const unsigned*)(uD + 512);
        unsigned vD3 = *(const unsigned*)(uD + 768);
        edgemath(cA, vA0, vA1, vA2, vA3);
        edgemath(cB, vB0, vB1, vB2, vB3);
        edgemath(cC, vC0, vC1, vC2, vC3);
        edgemath(cD, vD0, vD1, vD2, vD3);
    }
    for (; p + 1 < e; p += 2) {
        int2 cA = pairs[p], cB = pairs[p + 1];
        const uchar* uA = Ul + ((size_t)(cA.x & 0xFFFFF) << 10);
        const uchar* uB = Ul + ((size_t)(cB.x & 0xFFFFF) << 10);
        unsigned vA0 = *(const unsigned*)(uA);
        unsigned vA1 = *(const unsigned*)(uA + 256);
        unsigned vA2 = *(const unsigned*)(uA + 512);
        unsigned vA3 = *(const unsigned*)(uA + 768);
        unsigned vB0 = *(const unsigned*)(uB);
        unsigned vB1 = *(const unsigned*)(uB + 256);
        unsigned vB2 = *(const unsigned*)(uB + 512);
        unsigned vB3 = *(const unsigned*)(uB + 768);
        edgemath(cA, vA0, vA1, vA2, vA3);
        edgemath(cB, vB0, vB1, vB2, vB3);
    }
    if (p < e) {
        int2 cA = pairs[p];
        const uchar* uA = Ul + ((size_t)(cA.x & 0xFFFFF) << 10);
        unsigned vA0 = *(const unsigned*)(uA);
        unsigned vA1 = *(const unsigned*)(uA + 256);
        unsigned vA2 = *(const unsigned*)(uA + 512);
        unsigned vA3 = *(const unsigned*)(uA + 768);
        edgemath(cA, vA0, vA1, vA2, vA3);
    }

    float a[4];
    a[0] = bf2f(hu.x) + bb0 + a01[0];
    a[1] = bf2f(hu.y) + bb1 + a01[1];
    a[2] = bf2f(hu.z) + bb2 + a23[0];
    a[3] = bf2f(hu.w) + bb3 + a23[1];
    float sum = 0.f, sq = 0.f;
#pragma unroll
    for (int j = 0; j < 4; ++j) {
        float ex = __expf(-a[j]);
        a[j] = a[j] * __builtin_amdgcn_rcpf(1.f + ex);
        sum += a[j]; sq += a[j] * a[j];
    }
#pragma unroll
    for (int off = 32; off >= 1; off >>= 1) {
        sum += __shfl_xor(sum, off, 64);
        sq  += __shfl_xor(sq,  off, 64);
    }
    float mean = sum * (1.0f / 256.0f);
    float var = sq * (1.0f / 256.0f) - mean * mean;
    float rs = rsqrtf(var + LN_EPS);
#pragma unroll
    for (int j = 0; j < 4; ++j) {
        int c = c0 + j * 16;
        out[rowo + c] = (a[j] - mean) * rs * gamma[c] + beta[c];
    }
}

// ---------------------------------------------------------------------------
extern "C" void kernel_launch(void* const* d_in, const int* in_sizes, int n_in,
                              void* d_out, int out_size, void* d_ws, size_t ws_size,
                              hipStream_t stream) {
    const float* x      = (const float*)d_in[0];
    const int*   ei     = (const int*)d_in[1];
    const float* bases  = (const float*)d_in[2];
    const float* coeff  = (const float*)d_in[3];
    const float* w_self = (const float*)d_in[4];
    const float* b_self = (const float*)d_in[5];
    const float* gamma  = (const float*)d_in[6];
    const float* beta   = (const float*)d_in[7];
    float* out = (float*)d_out;

    ushort* BT  = (ushort*)d_ws;                          // 1280*256 bf16 (0.66 MB)
    ushort* xb  = BT + (size_t)1280 * D;                  // N*256 bf16 (51.2 MB)
    ushort* hb  = xb + (size_t)N_NODES * D;               // N*256 bf16 (51.2 MB)
    uchar*  U   = (uchar*)(hb + (size_t)N_NODES * D);     // N*1024 fp8 (102.4 MB)
    int* cntR   = (int*)(U + (size_t)N_NODES * 1024);     // 8N [dst][r] (3.2 MB)
    int* start  = cntR + (size_t)R_REL * N_NODES;         // N+1
    int* cursor = start + N_NODES + 1;                    // N
    int* sumsA  = cursor + N_NODES;                       // 98 (pad 128)
    int2* pairs = (int2*)(sumsA + 128);                   // ETOT int2 (2.56 MB)

    hipMemsetAsync(cntR, 0, (size_t)R_REL * N_NODES * sizeof(int), stream);

    k_prep<<<PREPX_NB + PREPB_NB + COUNT_NB, 256, 0, stream>>>(x, xb, w_self,
                                                               bases, BT, ei, cntR);
    k_scanA<<<SCAN_NB, 256, 0, stream>>>(cntR, start, sumsA);
    k_scanC<<<(N_NODES + 255) / 256, 256, 0, stream>>>(start, sumsA, cursor);
    k_scatter<<<(ETOT + 255) / 256, 256, 0, stream>>>(ei, cursor, cntR, pairs);
    k_gemm<<<NWG, 256, 0, stream>>>(xb, BT, hb, U);
    k_final<<<N_NODES / 4, 256, 0, stream>>>(out, hb, U, start, pairs, coeff,
                                             b_self, gamma, beta);
}